// Round 16
// baseline (1530.165 us; speedup 1.0000x reference)
//
#include <hip/hip_runtime.h>
#include <hip/hip_fp16.h>
#include <stdint.h>
#include <math.h>

#define HWS 16384
#define NPIX (16 * HWS)
#define T 256

typedef _Float16 h2 __attribute__((ext_vector_type(2)));
typedef float f4v __attribute__((ext_vector_type(4)));
union U4 { f4v v; float f[4]; h2 h[4]; };

// d_ws slot offsets (4B slots). Rows interleaved so one row base + immediate
// offsets serves a whole c-iteration. Slots [0, F_CFT) are the HOT tables,
// copied to LDS per block.
enum {
  H_W1P = 0,      // [24cp][24]  rb1 pairs
  F_B1  = 576,    // 24
  H_RB2 = 600,    // [24op][28]: W2row(2op)[12] | W2row(2op+1)[12] | {b2e,b2o,xse,xso}
  H_SC  = 1272,   // [48c][52]: M1A[12]|M1B[12]|M2A[12]|M2B[12]|{c1a,c1b,c2a,c2b}
  F_D4  = 3768,   // [24][4] {d1a,d1b,d2a,d2b}
  F_E4  = 3864,   // 4
  H_PV  = 3868,   // [48c][48]: P1[24]|P2[24]
  F_Q4  = 6172,   // [24][4] {q1l,q1h,q2l,q2h}
  F_BE1 = 6268,   // 24
  F_CFT = 6292,   // ---- hot region ends; f32 [96][48] cin-major (k0 only)
  F_BCF = 10900,  // 48
  F_WE1 = 10948,  // f32 [24][48] o-major (k0 only)
  F_WE2 = 12100,  // [24op][52]: we2row(2op)[24] | we2row(2op+1)[24] | {be2e,be2o,0,0}
  WS_TOTAL = 13348
};

struct PtrPack { const float* p[48]; };

__device__ __forceinline__ void bnst(const PtrPack& P, int bnb, int o, float& s, float& t) {
  float g = P.p[bnb][o], be = P.p[bnb + 1][o], m = P.p[bnb + 2][o], v = P.p[bnb + 3][o];
  s = g / sqrtf(v + 1e-5f);
  t = be - m * s;
}
__device__ __forceinline__ float KFv(const PtrPack& P, const float* kw, int bnb, int ok, int j) {
  float s, t; bnst(P, bnb, ok, s, t);
  float a = 0.f;
  for (int cc = 0; cc < 48; cc++) a += kw[ok * 48 + cc] * P.p[46][cc * 24 + j];
  return s * a;
}
__device__ __forceinline__ float BFv(const PtrPack& P, const float* kw, const float* kb, int bnb, int ok) {
  float s, t; bnst(P, bnb, ok, s, t);
  float a = kb[ok];
  for (int cc = 0; cc < 48; cc++) a += kw[ok * 48 + cc] * P.p[47][cc];
  return s * a + t;
}
__device__ __forceinline__ float WQf(const PtrPack& P, int o, int c) { float s, t; bnst(P, 16, o, s, t); return s * P.p[14][o * 48 + c]; }
__device__ __forceinline__ float BQf(const PtrPack& P, int o) { float s, t; bnst(P, 16, o, s, t); return s * P.p[15][o] + t; }
__device__ __forceinline__ float WVf(const PtrPack& P, int o, int c) { float s, t; bnst(P, 22, o, s, t); return s * P.p[20][o * 48 + c]; }
__device__ __forceinline__ float BVf(const PtrPack& P, int o) { float s, t; bnst(P, 22, o, s, t); return s * P.p[21][o] + t; }

__device__ float w1v(const PtrPack& P, int c, int o) { float s, t; bnst(P, 4, o, s, t); return s * P.p[2][o * 48 + c]; }
__device__ float w2v(const PtrPack& P, int o, int c) { float s, t; bnst(P, 10, o, s, t); return s * P.p[8][o * 24 + c]; }
__device__ float m_v(const PtrPack& P, int which, int c, int j) {
  float a = 0.f;
  if (which == 0)      for (int ok = 0; ok < 24; ok++) a += KFv(P, P.p[26], 28, ok, j) * WQf(P, ok, c);
  else if (which == 1) for (int ok = 0; ok < 24; ok++) a += KFv(P, P.p[26], 28, ok, j) * WQf(P, 24 + ok, c);
  else if (which == 2) for (int ok = 0; ok < 24; ok++) a += KFv(P, P.p[32], 34, ok, j) * WQf(P, ok, c);
  else                 for (int ok = 0; ok < 24; ok++) a += KFv(P, P.p[32], 34, ok, j) * WQf(P, 24 + ok, c);
  return a;
}
__device__ float p_v(const PtrPack& P, int which, int c, int o) {
  float a = 0.f;
  if (which == 0)      for (int jj = 0; jj < 24; jj++) a += P.p[44][o * 48 + jj] * WVf(P, jj, c);
  else if (which == 1) for (int jj = 0; jj < 24; jj++) a += P.p[44][o * 48 + jj] * WVf(P, 24 + jj, c);
  else if (which == 2) for (int jj = 0; jj < 24; jj++) a += P.p[44][o * 48 + 24 + jj] * WVf(P, jj, c);
  else                 for (int jj = 0; jj < 24; jj++) a += P.p[44][o * 48 + 24 + jj] * WVf(P, 24 + jj, c);
  return a;
}
__device__ float c_v(const PtrPack& P, int e, int c) {
  float a = 0.f;
  if (e == 0)      for (int ok = 0; ok < 24; ok++) a += BFv(P, P.p[26], P.p[27], 28, ok) * WQf(P, ok, c);
  else if (e == 1) for (int ok = 0; ok < 24; ok++) a += BFv(P, P.p[26], P.p[27], 28, ok) * WQf(P, 24 + ok, c);
  else if (e == 2) for (int ok = 0; ok < 24; ok++) a += BFv(P, P.p[32], P.p[33], 34, ok) * WQf(P, ok, c);
  else             for (int ok = 0; ok < 24; ok++) a += BFv(P, P.p[32], P.p[33], 34, ok) * WQf(P, 24 + ok, c);
  return a;
}
__device__ float d_v(const PtrPack& P, int e, int j) {
  float a = 0.f;
  if (e == 0)      for (int ok = 0; ok < 24; ok++) a += KFv(P, P.p[26], 28, ok, j) * BQf(P, ok);
  else if (e == 1) for (int ok = 0; ok < 24; ok++) a += KFv(P, P.p[26], 28, ok, j) * BQf(P, 24 + ok);
  else if (e == 2) for (int ok = 0; ok < 24; ok++) a += KFv(P, P.p[32], 34, ok, j) * BQf(P, ok);
  else             for (int ok = 0; ok < 24; ok++) a += KFv(P, P.p[32], 34, ok, j) * BQf(P, 24 + ok);
  return a;
}
__device__ float e_v(const PtrPack& P, int e) {
  float a = 0.f;
  if (e == 0)      for (int ok = 0; ok < 24; ok++) a += BFv(P, P.p[26], P.p[27], 28, ok) * BQf(P, ok);
  else if (e == 1) for (int ok = 0; ok < 24; ok++) a += BFv(P, P.p[26], P.p[27], 28, ok) * BQf(P, 24 + ok);
  else if (e == 2) for (int ok = 0; ok < 24; ok++) a += BFv(P, P.p[32], P.p[33], 34, ok) * BQf(P, ok);
  else             for (int ok = 0; ok < 24; ok++) a += BFv(P, P.p[32], P.p[33], 34, ok) * BQf(P, 24 + ok);
  return a;
}
__device__ float q_v(const PtrPack& P, int e, int o) {
  float a = 0.f;
  if (e == 0)      for (int jj = 0; jj < 24; jj++) a += P.p[44][o * 48 + jj] * BVf(P, jj);
  else if (e == 1) for (int jj = 0; jj < 24; jj++) a += P.p[44][o * 48 + jj] * BVf(P, 24 + jj);
  else if (e == 2) for (int jj = 0; jj < 24; jj++) a += P.p[44][o * 48 + 24 + jj] * BVf(P, jj);
  else             for (int jj = 0; jj < 24; jj++) a += P.p[44][o * 48 + 24 + jj] * BVf(P, 24 + jj);
  return a;
}

__device__ __forceinline__ float packh2(float a, float b) {
  __half2 h = __floats2half2_rn(a, b);
  union { __half2 h; float f; } x; x.h = h; return x.f;
}

__global__ void fold_kernel(PtrPack P, float* __restrict__ W) {
  int i = blockIdx.x * blockDim.x + threadIdx.x;
  if (i >= WS_TOTAL) return;
  float s, t;
  if (i < F_B1) { int cp = i / 24, o = i % 24; W[i] = packh2(w1v(P, 2 * cp, o), w1v(P, 2 * cp + 1, o)); }
  else if (i < H_RB2) { int o = i - F_B1; bnst(P, 4, o, s, t); W[i] = s * P.p[3][o] + t; }
  else if (i < H_SC) {
    int j = i - H_RB2; int op = j / 28, r = j % 28;
    if (r < 12)       W[i] = packh2(w2v(P, 2 * op, 2 * r), w2v(P, 2 * op, 2 * r + 1));
    else if (r < 24)  { int rr = r - 12; W[i] = packh2(w2v(P, 2 * op + 1, 2 * rr), w2v(P, 2 * op + 1, 2 * rr + 1)); }
    else {
      int e = r - 24; int o2 = 2 * op + (e & 1);
      bnst(P, 10, o2, s, t);
      W[i] = (e < 2) ? (s * P.p[9][o2] + t) : s;
    }
  }
  else if (i < F_D4) {
    int j = i - H_SC; int c = j / 52, r = j % 52;
    if (r < 12)       W[i] = packh2(m_v(P, 0, c, 2 * r), m_v(P, 0, c, 2 * r + 1));
    else if (r < 24)  { int rr = r - 12; W[i] = packh2(m_v(P, 1, c, 2 * rr), m_v(P, 1, c, 2 * rr + 1)); }
    else if (r < 36)  { int rr = r - 24; W[i] = packh2(m_v(P, 2, c, 2 * rr), m_v(P, 2, c, 2 * rr + 1)); }
    else if (r < 48)  { int rr = r - 36; W[i] = packh2(m_v(P, 3, c, 2 * rr), m_v(P, 3, c, 2 * rr + 1)); }
    else              W[i] = c_v(P, r - 48, c);
  }
  else if (i < F_E4) { int j = i - F_D4; W[i] = d_v(P, j % 4, j / 4); }
  else if (i < H_PV) { W[i] = e_v(P, i - F_E4); }
  else if (i < F_Q4) {
    int j = i - H_PV; int c = j / 48, r = j % 48;
    if (r < 24) W[i] = packh2(p_v(P, 0, c, r), p_v(P, 1, c, r));
    else        { int rr = r - 24; W[i] = packh2(p_v(P, 2, c, rr), p_v(P, 3, c, rr)); }
  }
  else if (i < F_BE1) { int j = i - F_Q4; W[i] = q_v(P, j % 4, j / 4); }
  else if (i < F_CFT) { W[i] = P.p[45][i - F_BE1]; }
  else if (i < F_BCF) { int j = i - F_CFT; int cin = j / 48, o = j % 48; bnst(P, 40, o, s, t); W[i] = s * P.p[38][o * 96 + cin]; }
  else if (i < F_WE1) { int o = i - F_BCF; bnst(P, 40, o, s, t); W[i] = s * P.p[39][o] + t; }
  else if (i < F_WE2) { W[i] = P.p[44][i - F_WE1]; }
  else {
    int j = i - F_WE2; int op = j / 52, r = j % 52;
    if (r < 24)       W[i] = P.p[46][(2 * op) * 24 + r];
    else if (r < 48)  W[i] = P.p[46][(2 * op + 1) * 24 + (r - 24)];
    else if (r == 48) W[i] = P.p[47][2 * op];
    else if (r == 49) W[i] = P.p[47][2 * op + 1];
    else              W[i] = 0.f;
  }
}

// ---------------- fused per-pixel forward ----------------

__device__ __forceinline__ float gelu_f(float x) {
  return 0.5f * x * (1.f + erff(x * 0.70710678118654752440f));
}
__device__ __forceinline__ float fdot2f(h2 a, h2 b, float c) {
#if __has_builtin(__builtin_amdgcn_fdot2)
  return __builtin_amdgcn_fdot2(a, b, c, false);
#else
  return fmaf((float)a[0], (float)b[0], fmaf((float)a[1], (float)b[1], c));
#endif
}
__device__ __forceinline__ h2 ash2(__half2 v) {
  union { __half2 a; h2 h; } u; u.a = v; return u.h;
}
// RNE packing (pkrtz's biased truncation failed accuracy in round 13)
__device__ __forceinline__ h2 pk(float a, float b) {
  return ash2(__floats2half2_rn(a, b));
}

__global__ __launch_bounds__(T)
void fused_main(const float* __restrict__ x0g,
                const float* __restrict__ x1g,
                const float* __restrict__ W,
                float* __restrict__ out) {
  __shared__ __half2 Xh[2][24][T];
  __shared__ __attribute__((aligned(16))) float Wl[F_CFT];  // hot weight tables in LDS (in-order lgkmcnt)
  const int tid = threadIdx.x;
  const int p = blockIdx.x * T + tid;
  const int b = p >> 14;
  const int n = p & (HWS - 1);

  for (int i = tid; i < F_CFT; i += T) Wl[i] = W[i];

  {
    const float* px0 = x0g + (size_t)b * 48 * HWS + n;
    const float* px1 = x1g + (size_t)b * 48 * HWS + n;
#pragma unroll 1
    for (int cp = 0; cp < 24; cp++) {
      Xh[0][cp][tid] = __floats2half2_rn(px0[(size_t)(2 * cp) * HWS], px0[(size_t)(2 * cp + 1) * HWS]);
      Xh[1][cp][tid] = __floats2half2_rn(px1[(size_t)(2 * cp) * HWS], px1[(size_t)(2 * cp + 1) * HWS]);
    }
  }
  __syncthreads();

  float h[24];

#pragma unroll 1
  for (int k = 0; k < 4; k++) {
    // ---- residual blocks ----
#pragma unroll 1
    for (int s = 0; s < 2; s++) {
      float r[24];
#pragma unroll
      for (int q = 0; q < 6; q++) {
        U4 bq; bq.v = *(const f4v*)&Wl[F_B1 + 4 * q];
        r[4 * q] = bq.f[0]; r[4 * q + 1] = bq.f[1]; r[4 * q + 2] = bq.f[2]; r[4 * q + 3] = bq.f[3];
      }
#pragma unroll 2
      for (int cp = 0; cp < 24; cp++) {
        h2 xp = ash2(Xh[s][cp][tid]);
        const int base = H_W1P + cp * 24;
#pragma unroll
        for (int q = 0; q < 6; q++) {
          U4 w; w.v = *(const f4v*)&Wl[base + 4 * q];
          r[4 * q]     = fdot2f(w.h[0], xp, r[4 * q]);
          r[4 * q + 1] = fdot2f(w.h[1], xp, r[4 * q + 1]);
          r[4 * q + 2] = fdot2f(w.h[2], xp, r[4 * q + 2]);
          r[4 * q + 3] = fdot2f(w.h[3], xp, r[4 * q + 3]);
        }
      }
#pragma unroll
      for (int o = 0; o < 24; o++) r[o] = fmaxf(r[o], 0.f);
      h2 rp[12];
#pragma unroll
      for (int j = 0; j < 12; j++) rp[j] = pk(r[2 * j], r[2 * j + 1]);

#pragma unroll 2
      for (int op = 0; op < 24; op++) {
        const int base = H_RB2 + op * 28;
        U4 bx; bx.v = *(const f4v*)&Wl[base + 24];
        float a0 = bx.f[0], a1 = bx.f[1];
#pragma unroll
        for (int q = 0; q < 3; q++) {
          U4 w; w.v = *(const f4v*)&Wl[base + 4 * q];
#pragma unroll
          for (int e = 0; e < 4; e++) a0 = fdot2f(w.h[e], rp[4 * q + e], a0);
        }
#pragma unroll
        for (int q = 0; q < 3; q++) {
          U4 w; w.v = *(const f4v*)&Wl[base + 12 + 4 * q];
#pragma unroll
          for (int e = 0; e < 4; e++) a1 = fdot2f(w.h[e], rp[4 * q + e], a1);
        }
        __half2 u = Xh[s][op][tid];
        float n0 = fmaxf(fmaf(bx.f[2], __low2float(u), a0), 0.f);
        float n1 = fmaxf(fmaf(bx.f[3], __high2float(u), a1), 0.f);
        Xh[s][op][tid] = __floats2half2_rn(n0, n1);
      }
    }

    // ---- k==0: cf + emb1 -> h (runs once; global s_load path, amortized) ----
    if (k == 0) {
      float tv[48];
#pragma unroll
      for (int o = 0; o < 48; o++) tv[o] = W[F_BCF + o];
#pragma unroll 1
      for (int s = 0; s < 2; s++) {
#pragma unroll 1
        for (int cp = 0; cp < 24; cp++) {
          __half2 u = Xh[s][cp][tid];
          float x0c = __low2float(u), x1c = __high2float(u);
          const float* w0 = &W[F_CFT + (s * 48 + 2 * cp) * 48];
#pragma unroll
          for (int o = 0; o < 48; o++) tv[o] = fmaf(w0[o], x0c, tv[o]);
#pragma unroll
          for (int o = 0; o < 48; o++) tv[o] = fmaf(w0[48 + o], x1c, tv[o]);
        }
      }
#pragma unroll
      for (int o = 0; o < 48; o++) tv[o] = fmaxf(tv[o], 0.f);
#pragma unroll 2
      for (int o = 0; o < 24; o++) {
        const float* w0 = &W[F_WE1 + o * 48];
        float a = Wl[F_BE1 + o];
#pragma unroll
        for (int c = 0; c < 48; c++) a = fmaf(w0[c], tv[c], a);
        h[o] = gelu_f(a);
      }
    }

    // ---- scores ----
    float s1[4], s2[4];
    {
      U4 e4; e4.v = *(const f4v*)&Wl[F_E4];
      float b1a = e4.f[0], b1b = e4.f[1], b2a = e4.f[2], b2b = e4.f[3];
#pragma unroll
      for (int j = 0; j < 24; j++) {
        U4 d; d.v = *(const f4v*)&Wl[F_D4 + 4 * j];
        b1a = fmaf(d.f[0], h[j], b1a);
        b1b = fmaf(d.f[1], h[j], b1b);
        b2a = fmaf(d.f[2], h[j], b2a);
        b2b = fmaf(d.f[3], h[j], b2b);
      }
      s1[0] = b1a; s1[2] = b1a; s1[1] = b1b; s1[3] = b1b;
      s2[0] = b2a; s2[2] = b2a; s2[1] = b2b; s2[3] = b2b;
    }
    h2 hp[12];
#pragma unroll
    for (int j = 0; j < 12; j++) hp[j] = pk(h[2 * j], h[2 * j + 1]);

#pragma unroll 1
    for (int cp = 0; cp < 24; cp++) {
      __half2 u0 = Xh[0][cp][tid], u1 = Xh[1][cp][tid];
#pragma unroll
      for (int ch = 0; ch < 2; ch++) {
        int c = 2 * cp + ch;
        const int base = H_SC + c * 52;
        U4 cc; cc.v = *(const f4v*)&Wl[base + 48];
        float z1a = cc.f[0], z1b = cc.f[1], z2a = cc.f[2], z2b = cc.f[3];
#pragma unroll
        for (int q = 0; q < 3; q++) {
          U4 w; w.v = *(const f4v*)&Wl[base + 4 * q];
#pragma unroll
          for (int e = 0; e < 4; e++) z1a = fdot2f(w.h[e], hp[4 * q + e], z1a);
        }
#pragma unroll
        for (int q = 0; q < 3; q++) {
          U4 w; w.v = *(const f4v*)&Wl[base + 12 + 4 * q];
#pragma unroll
          for (int e = 0; e < 4; e++) z1b = fdot2f(w.h[e], hp[4 * q + e], z1b);
        }
#pragma unroll
        for (int q = 0; q < 3; q++) {
          U4 w; w.v = *(const f4v*)&Wl[base + 24 + 4 * q];
#pragma unroll
          for (int e = 0; e < 4; e++) z2a = fdot2f(w.h[e], hp[4 * q + e], z2a);
        }
#pragma unroll
        for (int q = 0; q < 3; q++) {
          U4 w; w.v = *(const f4v*)&Wl[base + 36 + 4 * q];
#pragma unroll
          for (int e = 0; e < 4; e++) z2b = fdot2f(w.h[e], hp[4 * q + e], z2b);
        }
        float x0 = ch ? __high2float(u0) : __low2float(u0);
        float x1 = ch ? __high2float(u1) : __low2float(u1);
        s1[0] = fmaf(x0, z1a, s1[0]); s1[1] = fmaf(x0, z1b, s1[1]);
        s1[2] = fmaf(x1, z1a, s1[2]); s1[3] = fmaf(x1, z1b, s1[3]);
        s2[0] = fmaf(x0, z2a, s2[0]); s2[1] = fmaf(x0, z2b, s2[1]);
        s2[2] = fmaf(x1, z2a, s2[2]); s2[3] = fmaf(x1, z2b, s2[3]);
      }
    }
    // softmax over 4
    {
      float m1 = fmaxf(fmaxf(s1[0], s1[1]), fmaxf(s1[2], s1[3]));
      float e0 = __expf(s1[0] - m1), e1 = __expf(s1[1] - m1), e2 = __expf(s1[2] - m1), e3 = __expf(s1[3] - m1);
      float inv = 1.f / (e0 + e1 + e2 + e3);
      s1[0] = e0 * inv; s1[1] = e1 * inv; s1[2] = e2 * inv; s1[3] = e3 * inv;
      float m2 = fmaxf(fmaxf(s2[0], s2[1]), fmaxf(s2[2], s2[3]));
      float f0 = __expf(s2[0] - m2), f1 = __expf(s2[1] - m2), f2 = __expf(s2[2] - m2), f3 = __expf(s2[3] - m2);
      float jnv = 1.f / (f0 + f1 + f2 + f3);
      s2[0] = f0 * jnv; s2[1] = f1 * jnv; s2[2] = f2 * jnv; s2[3] = f3 * jnv;
    }

    // ---- values fused with emb1 ----
    float hv[24];
    {
      float q1l = s1[0] + s1[2], q1h = s1[1] + s1[3];
      float q2l = s2[0] + s2[2], q2h = s2[1] + s2[3];
#pragma unroll
      for (int o = 0; o < 24; o++) {
        U4 qq; qq.v = *(const f4v*)&Wl[F_Q4 + 4 * o];
        hv[o] = fmaf(q1l, qq.f[0], fmaf(q1h, qq.f[1], fmaf(q2l, qq.f[2], fmaf(q2h, qq.f[3], Wl[F_BE1 + o]))));
      }
    }
#pragma unroll 1
    for (int cp = 0; cp < 24; cp++) {
      __half2 u0 = Xh[0][cp][tid], u1 = Xh[1][cp][tid];
#pragma unroll
      for (int ch = 0; ch < 2; ch++) {
        int c = 2 * cp + ch;
        float x0 = ch ? __high2float(u0) : __low2float(u0);
        float x1 = ch ? __high2float(u1) : __low2float(u1);
        float cA = fmaf(s1[0], x0, s1[2] * x1);
        float cB = fmaf(s1[1], x0, s1[3] * x1);
        float cC = fmaf(s2[0], x0, s2[2] * x1);
        float cD = fmaf(s2[1], x0, s2[3] * x1);
        h2 pAB = pk(cA, cB), pCD = pk(cC, cD);
        const int base = H_PV + c * 48;
#pragma unroll
        for (int q = 0; q < 6; q++) {
          U4 w; w.v = *(const f4v*)&Wl[base + 4 * q];
#pragma unroll
          for (int e = 0; e < 4; e++) hv[4 * q + e] = fdot2f(w.h[e], pAB, hv[4 * q + e]);
        }
#pragma unroll
        for (int q = 0; q < 6; q++) {
          U4 w; w.v = *(const f4v*)&Wl[base + 24 + 4 * q];
#pragma unroll
          for (int e = 0; e < 4; e++) hv[4 * q + e] = fdot2f(w.h[e], pCD, hv[4 * q + e]);
        }
      }
    }
#pragma unroll
    for (int o = 0; o < 24; o++) h[o] = gelu_f(hv[o]);
  }

  // ---- final: out = WE2 h + BE2 (global s_load path, runs once) ----
  float* po = out + (size_t)b * 48 * HWS + n;
#pragma unroll 1
  for (int op = 0; op < 24; op++) {
    const float* w0 = &W[F_WE2 + op * 52];
    float a0 = w0[48], a1 = w0[49];
#pragma unroll
    for (int j = 0; j < 24; j++) a0 = fmaf(w0[j], h[j], a0);
#pragma unroll
    for (int j = 0; j < 24; j++) a1 = fmaf(w0[24 + j], h[j], a1);
    po[(size_t)(2 * op) * HWS] = a0;
    po[(size_t)(2 * op + 1) * HWS] = a1;
  }
}

extern "C" void kernel_launch(void* const* d_in, const int* in_sizes, int n_in,
                              void* d_out, int out_size, void* d_ws, size_t ws_size,
                              hipStream_t stream) {
  PtrPack P;
  for (int i = 0; i < 48; i++) P.p[i] = (const float*)d_in[i];
  float* W = (float*)d_ws;

  fold_kernel<<<(WS_TOTAL + 255) / 256, 256, 0, stream>>>(P, W);
  fused_main<<<NPIX / T, T, 0, stream>>>(P.p[0], P.p[1], W, (float*)d_out);
}

// Round 17
// 1079.587 us; speedup vs baseline: 1.4174x; 1.4174x over previous
//
#include <hip/hip_runtime.h>
#include <hip/hip_fp16.h>
#include <stdint.h>
#include <math.h>

#define HWS 16384
#define NPIX (16 * HWS)
#define T 128          // threads per block; each thread owns 2 pixels (tid, tid+128)
#define BPX 256        // pixels per block

typedef _Float16 h2 __attribute__((ext_vector_type(2)));
typedef float f4v __attribute__((ext_vector_type(4)));
union U4 { f4v v; float f[4]; h2 h[4]; };

// d_ws slot offsets (4B slots). Rows interleaved so one row base + immediate
// offsets serves a whole c-iteration. Weights via s_load (SGPR) — the only
// path that doesn't cost VGPRs (r15/r16 falsified VMEM/LDS alternatives).
enum {
  H_W1P = 0,      // [24cp][24]  rb1 pairs
  F_B1  = 576,    // 24
  H_RB2 = 600,    // [24op][28]: W2row(2op)[12] | W2row(2op+1)[12] | {b2e,b2o,xse,xso}
  H_SC  = 1272,   // [48c][52]: M1A[12]|M1B[12]|M2A[12]|M2B[12]|{c1a,c1b,c2a,c2b}
  F_D4  = 3768,   // [24][4] {d1a,d1b,d2a,d2b}
  F_E4  = 3864,   // 4
  H_PV  = 3868,   // [48c][48]: P1[24]|P2[24]
  F_Q4  = 6172,   // [24][4] {q1l,q1h,q2l,q2h}
  F_BE1 = 6268,   // 24
  F_CFT = 6292,   // f32 [96][48] cin-major (k0 only)
  F_BCF = 10900,  // 48
  F_WE1 = 10948,  // f32 [24][48] o-major (k0 only)
  F_WE2 = 12100,  // [24op][52]: we2row(2op)[24] | we2row(2op+1)[24] | {be2e,be2o,0,0}
  WS_TOTAL = 13348
};

struct PtrPack { const float* p[48]; };

__device__ __forceinline__ void bnst(const PtrPack& P, int bnb, int o, float& s, float& t) {
  float g = P.p[bnb][o], be = P.p[bnb + 1][o], m = P.p[bnb + 2][o], v = P.p[bnb + 3][o];
  s = g / sqrtf(v + 1e-5f);
  t = be - m * s;
}
__device__ __forceinline__ float KFv(const PtrPack& P, const float* kw, int bnb, int ok, int j) {
  float s, t; bnst(P, bnb, ok, s, t);
  float a = 0.f;
  for (int cc = 0; cc < 48; cc++) a += kw[ok * 48 + cc] * P.p[46][cc * 24 + j];
  return s * a;
}
__device__ __forceinline__ float BFv(const PtrPack& P, const float* kw, const float* kb, int bnb, int ok) {
  float s, t; bnst(P, bnb, ok, s, t);
  float a = kb[ok];
  for (int cc = 0; cc < 48; cc++) a += kw[ok * 48 + cc] * P.p[47][cc];
  return s * a + t;
}
__device__ __forceinline__ float WQf(const PtrPack& P, int o, int c) { float s, t; bnst(P, 16, o, s, t); return s * P.p[14][o * 48 + c]; }
__device__ __forceinline__ float BQf(const PtrPack& P, int o) { float s, t; bnst(P, 16, o, s, t); return s * P.p[15][o] + t; }
__device__ __forceinline__ float WVf(const PtrPack& P, int o, int c) { float s, t; bnst(P, 22, o, s, t); return s * P.p[20][o * 48 + c]; }
__device__ __forceinline__ float BVf(const PtrPack& P, int o) { float s, t; bnst(P, 22, o, s, t); return s * P.p[21][o] + t; }

__device__ float w1v(const PtrPack& P, int c, int o) { float s, t; bnst(P, 4, o, s, t); return s * P.p[2][o * 48 + c]; }
__device__ float w2v(const PtrPack& P, int o, int c) { float s, t; bnst(P, 10, o, s, t); return s * P.p[8][o * 24 + c]; }
__device__ float m_v(const PtrPack& P, int which, int c, int j) {
  float a = 0.f;
  if (which == 0)      for (int ok = 0; ok < 24; ok++) a += KFv(P, P.p[26], 28, ok, j) * WQf(P, ok, c);
  else if (which == 1) for (int ok = 0; ok < 24; ok++) a += KFv(P, P.p[26], 28, ok, j) * WQf(P, 24 + ok, c);
  else if (which == 2) for (int ok = 0; ok < 24; ok++) a += KFv(P, P.p[32], 34, ok, j) * WQf(P, ok, c);
  else                 for (int ok = 0; ok < 24; ok++) a += KFv(P, P.p[32], 34, ok, j) * WQf(P, 24 + ok, c);
  return a;
}
__device__ float p_v(const PtrPack& P, int which, int c, int o) {
  float a = 0.f;
  if (which == 0)      for (int jj = 0; jj < 24; jj++) a += P.p[44][o * 48 + jj] * WVf(P, jj, c);
  else if (which == 1) for (int jj = 0; jj < 24; jj++) a += P.p[44][o * 48 + jj] * WVf(P, 24 + jj, c);
  else if (which == 2) for (int jj = 0; jj < 24; jj++) a += P.p[44][o * 48 + 24 + jj] * WVf(P, jj, c);
  else                 for (int jj = 0; jj < 24; jj++) a += P.p[44][o * 48 + 24 + jj] * WVf(P, 24 + jj, c);
  return a;
}
__device__ float c_v(const PtrPack& P, int e, int c) {
  float a = 0.f;
  if (e == 0)      for (int ok = 0; ok < 24; ok++) a += BFv(P, P.p[26], P.p[27], 28, ok) * WQf(P, ok, c);
  else if (e == 1) for (int ok = 0; ok < 24; ok++) a += BFv(P, P.p[26], P.p[27], 28, ok) * WQf(P, 24 + ok, c);
  else if (e == 2) for (int ok = 0; ok < 24; ok++) a += BFv(P, P.p[32], P.p[33], 34, ok) * WQf(P, ok, c);
  else             for (int ok = 0; ok < 24; ok++) a += BFv(P, P.p[32], P.p[33], 34, ok) * WQf(P, 24 + ok, c);
  return a;
}
__device__ float d_v(const PtrPack& P, int e, int j) {
  float a = 0.f;
  if (e == 0)      for (int ok = 0; ok < 24; ok++) a += KFv(P, P.p[26], 28, ok, j) * BQf(P, ok);
  else if (e == 1) for (int ok = 0; ok < 24; ok++) a += KFv(P, P.p[26], 28, ok, j) * BQf(P, 24 + ok);
  else if (e == 2) for (int ok = 0; ok < 24; ok++) a += KFv(P, P.p[32], 34, ok, j) * BQf(P, ok);
  else             for (int ok = 0; ok < 24; ok++) a += KFv(P, P.p[32], 34, ok, j) * BQf(P, 24 + ok);
  return a;
}
__device__ float e_v(const PtrPack& P, int e) {
  float a = 0.f;
  if (e == 0)      for (int ok = 0; ok < 24; ok++) a += BFv(P, P.p[26], P.p[27], 28, ok) * BQf(P, ok);
  else if (e == 1) for (int ok = 0; ok < 24; ok++) a += BFv(P, P.p[26], P.p[27], 28, ok) * BQf(P, 24 + ok);
  else if (e == 2) for (int ok = 0; ok < 24; ok++) a += BFv(P, P.p[32], P.p[33], 34, ok) * BQf(P, ok);
  else             for (int ok = 0; ok < 24; ok++) a += BFv(P, P.p[32], P.p[33], 34, ok) * BQf(P, 24 + ok);
  return a;
}
__device__ float q_v(const PtrPack& P, int e, int o) {
  float a = 0.f;
  if (e == 0)      for (int jj = 0; jj < 24; jj++) a += P.p[44][o * 48 + jj] * BVf(P, jj);
  else if (e == 1) for (int jj = 0; jj < 24; jj++) a += P.p[44][o * 48 + jj] * BVf(P, 24 + jj);
  else if (e == 2) for (int jj = 0; jj < 24; jj++) a += P.p[44][o * 48 + 24 + jj] * BVf(P, jj);
  else             for (int jj = 0; jj < 24; jj++) a += P.p[44][o * 48 + 24 + jj] * BVf(P, 24 + jj);
  return a;
}

__device__ __forceinline__ float packh2(float a, float b) {
  __half2 h = __floats2half2_rn(a, b);
  union { __half2 h; float f; } x; x.h = h; return x.f;
}

__global__ void fold_kernel(PtrPack P, float* __restrict__ W) {
  int i = blockIdx.x * blockDim.x + threadIdx.x;
  if (i >= WS_TOTAL) return;
  float s, t;
  if (i < F_B1) { int cp = i / 24, o = i % 24; W[i] = packh2(w1v(P, 2 * cp, o), w1v(P, 2 * cp + 1, o)); }
  else if (i < H_RB2) { int o = i - F_B1; bnst(P, 4, o, s, t); W[i] = s * P.p[3][o] + t; }
  else if (i < H_SC) {
    int j = i - H_RB2; int op = j / 28, r = j % 28;
    if (r < 12)       W[i] = packh2(w2v(P, 2 * op, 2 * r), w2v(P, 2 * op, 2 * r + 1));
    else if (r < 24)  { int rr = r - 12; W[i] = packh2(w2v(P, 2 * op + 1, 2 * rr), w2v(P, 2 * op + 1, 2 * rr + 1)); }
    else {
      int e = r - 24; int o2 = 2 * op + (e & 1);
      bnst(P, 10, o2, s, t);
      W[i] = (e < 2) ? (s * P.p[9][o2] + t) : s;
    }
  }
  else if (i < F_D4) {
    int j = i - H_SC; int c = j / 52, r = j % 52;
    if (r < 12)       W[i] = packh2(m_v(P, 0, c, 2 * r), m_v(P, 0, c, 2 * r + 1));
    else if (r < 24)  { int rr = r - 12; W[i] = packh2(m_v(P, 1, c, 2 * rr), m_v(P, 1, c, 2 * rr + 1)); }
    else if (r < 36)  { int rr = r - 24; W[i] = packh2(m_v(P, 2, c, 2 * rr), m_v(P, 2, c, 2 * rr + 1)); }
    else if (r < 48)  { int rr = r - 36; W[i] = packh2(m_v(P, 3, c, 2 * rr), m_v(P, 3, c, 2 * rr + 1)); }
    else              W[i] = c_v(P, r - 48, c);
  }
  else if (i < F_E4) { int j = i - F_D4; W[i] = d_v(P, j % 4, j / 4); }
  else if (i < H_PV) { W[i] = e_v(P, i - F_E4); }
  else if (i < F_Q4) {
    int j = i - H_PV; int c = j / 48, r = j % 48;
    if (r < 24) W[i] = packh2(p_v(P, 0, c, r), p_v(P, 1, c, r));
    else        { int rr = r - 24; W[i] = packh2(p_v(P, 2, c, rr), p_v(P, 3, c, rr)); }
  }
  else if (i < F_BE1) { int j = i - F_Q4; W[i] = q_v(P, j % 4, j / 4); }
  else if (i < F_CFT) { W[i] = P.p[45][i - F_BE1]; }
  else if (i < F_BCF) { int j = i - F_CFT; int cin = j / 48, o = j % 48; bnst(P, 40, o, s, t); W[i] = s * P.p[38][o * 96 + cin]; }
  else if (i < F_WE1) { int o = i - F_BCF; bnst(P, 40, o, s, t); W[i] = s * P.p[39][o] + t; }
  else if (i < F_WE2) { W[i] = P.p[44][i - F_WE1]; }
  else {
    int j = i - F_WE2; int op = j / 52, r = j % 52;
    if (r < 24)       W[i] = P.p[46][(2 * op) * 24 + r];
    else if (r < 48)  W[i] = P.p[46][(2 * op + 1) * 24 + (r - 24)];
    else if (r == 48) W[i] = P.p[47][2 * op];
    else if (r == 49) W[i] = P.p[47][2 * op + 1];
    else              W[i] = 0.f;
  }
}

// ---------------- fused per-pixel forward, 2 pixels per thread ----------------

__device__ __forceinline__ float gelu_f(float x) {
  return 0.5f * x * (1.f + erff(x * 0.70710678118654752440f));
}
__device__ __forceinline__ float fdot2f(h2 a, h2 b, float c) {
#if __has_builtin(__builtin_amdgcn_fdot2)
  return __builtin_amdgcn_fdot2(a, b, c, false);
#else
  return fmaf((float)a[0], (float)b[0], fmaf((float)a[1], (float)b[1], c));
#endif
}
__device__ __forceinline__ h2 ash2(__half2 v) {
  union { __half2 a; h2 h; } u; u.a = v; return u.h;
}
// RNE packing (pkrtz's biased truncation failed accuracy in round 13)
__device__ __forceinline__ h2 pk(float a, float b) {
  return ash2(__floats2half2_rn(a, b));
}
__device__ __forceinline__ U4 ld4(const float* __restrict__ W, int off) {
  U4 u; u.v = *(const f4v*)&W[off]; return u;
}

__global__ __launch_bounds__(T)
void fused_main(const float* __restrict__ x0g,
                const float* __restrict__ x1g,
                const float* __restrict__ W,
                float* __restrict__ out) {
  __shared__ __half2 Xh[2][24][BPX];
  const int tid = threadIdx.x;
  const int p0 = blockIdx.x * BPX + tid;   // pixel A; pixel B = p0 + 128 (same batch: 16384 % 256 == 0)
  const int b = p0 >> 14;
  const int n = p0 & (HWS - 1);

  {
    const float* px0 = x0g + (size_t)b * 48 * HWS + n;
    const float* px1 = x1g + (size_t)b * 48 * HWS + n;
#pragma unroll 1
    for (int cp = 0; cp < 24; cp++) {
      Xh[0][cp][tid]       = __floats2half2_rn(px0[(size_t)(2 * cp) * HWS], px0[(size_t)(2 * cp + 1) * HWS]);
      Xh[1][cp][tid]       = __floats2half2_rn(px1[(size_t)(2 * cp) * HWS], px1[(size_t)(2 * cp + 1) * HWS]);
      Xh[0][cp][tid + 128] = __floats2half2_rn(px0[(size_t)(2 * cp) * HWS + 128], px0[(size_t)(2 * cp + 1) * HWS + 128]);
      Xh[1][cp][tid + 128] = __floats2half2_rn(px1[(size_t)(2 * cp) * HWS + 128], px1[(size_t)(2 * cp + 1) * HWS + 128]);
    }
  }

  float hA[24], hB[24];

#pragma unroll 1
  for (int k = 0; k < 4; k++) {
    // ---- residual blocks ----
#pragma unroll 1
    for (int s = 0; s < 2; s++) {
      float rA[24], rB[24];
#pragma unroll
      for (int q = 0; q < 6; q++) {
        U4 bq = ld4(W, F_B1 + 4 * q);
#pragma unroll
        for (int e = 0; e < 4; e++) { rA[4 * q + e] = bq.f[e]; rB[4 * q + e] = bq.f[e]; }
      }
#pragma unroll 2
      for (int cp = 0; cp < 24; cp++) {
        h2 xpA = ash2(Xh[s][cp][tid]);
        h2 xpB = ash2(Xh[s][cp][tid + 128]);
        const int base = H_W1P + cp * 24;
#pragma unroll
        for (int q = 0; q < 6; q++) {
          U4 w = ld4(W, base + 4 * q);
#pragma unroll
          for (int e = 0; e < 4; e++) {
            rA[4 * q + e] = fdot2f(w.h[e], xpA, rA[4 * q + e]);
            rB[4 * q + e] = fdot2f(w.h[e], xpB, rB[4 * q + e]);
          }
        }
      }
      h2 rpA[12], rpB[12];
#pragma unroll
      for (int j = 0; j < 12; j++) {
        rpA[j] = pk(fmaxf(rA[2 * j], 0.f), fmaxf(rA[2 * j + 1], 0.f));
        rpB[j] = pk(fmaxf(rB[2 * j], 0.f), fmaxf(rB[2 * j + 1], 0.f));
      }

#pragma unroll 2
      for (int op = 0; op < 24; op++) {
        const int base = H_RB2 + op * 28;
        U4 bx = ld4(W, base + 24);
        float a0A = bx.f[0], a1A = bx.f[1], a0B = bx.f[0], a1B = bx.f[1];
#pragma unroll
        for (int q = 0; q < 3; q++) {
          U4 w = ld4(W, base + 4 * q);
#pragma unroll
          for (int e = 0; e < 4; e++) {
            a0A = fdot2f(w.h[e], rpA[4 * q + e], a0A);
            a0B = fdot2f(w.h[e], rpB[4 * q + e], a0B);
          }
        }
#pragma unroll
        for (int q = 0; q < 3; q++) {
          U4 w = ld4(W, base + 12 + 4 * q);
#pragma unroll
          for (int e = 0; e < 4; e++) {
            a1A = fdot2f(w.h[e], rpA[4 * q + e], a1A);
            a1B = fdot2f(w.h[e], rpB[4 * q + e], a1B);
          }
        }
        __half2 uA = Xh[s][op][tid];
        __half2 uB = Xh[s][op][tid + 128];
        float n0A = fmaxf(fmaf(bx.f[2], __low2float(uA), a0A), 0.f);
        float n1A = fmaxf(fmaf(bx.f[3], __high2float(uA), a1A), 0.f);
        float n0B = fmaxf(fmaf(bx.f[2], __low2float(uB), a0B), 0.f);
        float n1B = fmaxf(fmaf(bx.f[3], __high2float(uB), a1B), 0.f);
        Xh[s][op][tid]       = __floats2half2_rn(n0A, n1A);
        Xh[s][op][tid + 128] = __floats2half2_rn(n0B, n1B);
      }
    }

    // ---- k==0: cf + emb1 -> h (runs once) ----
    if (k == 0) {
      float tvA[48], tvB[48];
#pragma unroll
      for (int o = 0; o < 48; o++) { float bb = W[F_BCF + o]; tvA[o] = bb; tvB[o] = bb; }
#pragma unroll 1
      for (int s = 0; s < 2; s++) {
#pragma unroll 1
        for (int cp = 0; cp < 24; cp++) {
          __half2 uA = Xh[s][cp][tid];
          __half2 uB = Xh[s][cp][tid + 128];
          float x0A = __low2float(uA), x1A = __high2float(uA);
          float x0B = __low2float(uB), x1B = __high2float(uB);
          const float* w0 = &W[F_CFT + (s * 48 + 2 * cp) * 48];
#pragma unroll
          for (int o = 0; o < 48; o++) {
            float wa = w0[o], wb = w0[48 + o];
            tvA[o] = fmaf(wa, x0A, fmaf(wb, x1A, tvA[o]));
            tvB[o] = fmaf(wa, x0B, fmaf(wb, x1B, tvB[o]));
          }
        }
      }
#pragma unroll
      for (int o = 0; o < 48; o++) { tvA[o] = fmaxf(tvA[o], 0.f); tvB[o] = fmaxf(tvB[o], 0.f); }
#pragma unroll 2
      for (int o = 0; o < 24; o++) {
        const float* w0 = &W[F_WE1 + o * 48];
        float aA = W[F_BE1 + o], aB = aA;
#pragma unroll
        for (int c = 0; c < 48; c++) { float ww = w0[c]; aA = fmaf(ww, tvA[c], aA); aB = fmaf(ww, tvB[c], aB); }
        hA[o] = gelu_f(aA);
        hB[o] = gelu_f(aB);
      }
    }

    // ---- scores ----
    float s1A[4], s2A[4], s1B[4], s2B[4];
    {
      U4 e4 = ld4(W, F_E4);
      float b1aA = e4.f[0], b1bA = e4.f[1], b2aA = e4.f[2], b2bA = e4.f[3];
      float b1aB = e4.f[0], b1bB = e4.f[1], b2aB = e4.f[2], b2bB = e4.f[3];
#pragma unroll
      for (int j = 0; j < 24; j++) {
        U4 d = ld4(W, F_D4 + 4 * j);
        b1aA = fmaf(d.f[0], hA[j], b1aA); b1bA = fmaf(d.f[1], hA[j], b1bA);
        b2aA = fmaf(d.f[2], hA[j], b2aA); b2bA = fmaf(d.f[3], hA[j], b2bA);
        b1aB = fmaf(d.f[0], hB[j], b1aB); b1bB = fmaf(d.f[1], hB[j], b1bB);
        b2aB = fmaf(d.f[2], hB[j], b2aB); b2bB = fmaf(d.f[3], hB[j], b2bB);
      }
      s1A[0] = b1aA; s1A[2] = b1aA; s1A[1] = b1bA; s1A[3] = b1bA;
      s2A[0] = b2aA; s2A[2] = b2aA; s2A[1] = b2bA; s2A[3] = b2bA;
      s1B[0] = b1aB; s1B[2] = b1aB; s1B[1] = b1bB; s1B[3] = b1bB;
      s2B[0] = b2aB; s2B[2] = b2aB; s2B[1] = b2bB; s2B[3] = b2bB;
    }
    h2 hpA[12], hpB[12];
#pragma unroll
    for (int j = 0; j < 12; j++) {
      hpA[j] = pk(hA[2 * j], hA[2 * j + 1]);
      hpB[j] = pk(hB[2 * j], hB[2 * j + 1]);
    }

#pragma unroll 1
    for (int cp = 0; cp < 24; cp++) {
      __half2 u0A = Xh[0][cp][tid], u1A = Xh[1][cp][tid];
      __half2 u0B = Xh[0][cp][tid + 128], u1B = Xh[1][cp][tid + 128];
#pragma unroll
      for (int ch = 0; ch < 2; ch++) {
        int c = 2 * cp + ch;
        const int base = H_SC + c * 52;
        U4 cc = ld4(W, base + 48);
        float z1aA = cc.f[0], z1bA = cc.f[1], z2aA = cc.f[2], z2bA = cc.f[3];
        float z1aB = cc.f[0], z1bB = cc.f[1], z2aB = cc.f[2], z2bB = cc.f[3];
#pragma unroll
        for (int q = 0; q < 3; q++) {
          U4 w = ld4(W, base + 4 * q);
#pragma unroll
          for (int e = 0; e < 4; e++) { z1aA = fdot2f(w.h[e], hpA[4 * q + e], z1aA); z1aB = fdot2f(w.h[e], hpB[4 * q + e], z1aB); }
        }
#pragma unroll
        for (int q = 0; q < 3; q++) {
          U4 w = ld4(W, base + 12 + 4 * q);
#pragma unroll
          for (int e = 0; e < 4; e++) { z1bA = fdot2f(w.h[e], hpA[4 * q + e], z1bA); z1bB = fdot2f(w.h[e], hpB[4 * q + e], z1bB); }
        }
#pragma unroll
        for (int q = 0; q < 3; q++) {
          U4 w = ld4(W, base + 24 + 4 * q);
#pragma unroll
          for (int e = 0; e < 4; e++) { z2aA = fdot2f(w.h[e], hpA[4 * q + e], z2aA); z2aB = fdot2f(w.h[e], hpB[4 * q + e], z2aB); }
        }
#pragma unroll
        for (int q = 0; q < 3; q++) {
          U4 w = ld4(W, base + 36 + 4 * q);
#pragma unroll
          for (int e = 0; e < 4; e++) { z2bA = fdot2f(w.h[e], hpA[4 * q + e], z2bA); z2bB = fdot2f(w.h[e], hpB[4 * q + e], z2bB); }
        }
        float x0A = ch ? __high2float(u0A) : __low2float(u0A);
        float x1A = ch ? __high2float(u1A) : __low2float(u1A);
        float x0B = ch ? __high2float(u0B) : __low2float(u0B);
        float x1B = ch ? __high2float(u1B) : __low2float(u1B);
        s1A[0] = fmaf(x0A, z1aA, s1A[0]); s1A[1] = fmaf(x0A, z1bA, s1A[1]);
        s1A[2] = fmaf(x1A, z1aA, s1A[2]); s1A[3] = fmaf(x1A, z1bA, s1A[3]);
        s2A[0] = fmaf(x0A, z2aA, s2A[0]); s2A[1] = fmaf(x0A, z2bA, s2A[1]);
        s2A[2] = fmaf(x1A, z2aA, s2A[2]); s2A[3] = fmaf(x1A, z2bA, s2A[3]);
        s1B[0] = fmaf(x0B, z1aB, s1B[0]); s1B[1] = fmaf(x0B, z1bB, s1B[1]);
        s1B[2] = fmaf(x1B, z1aB, s1B[2]); s1B[3] = fmaf(x1B, z1bB, s1B[3]);
        s2B[0] = fmaf(x0B, z2aB, s2B[0]); s2B[1] = fmaf(x0B, z2bB, s2B[1]);
        s2B[2] = fmaf(x1B, z2aB, s2B[2]); s2B[3] = fmaf(x1B, z2bB, s2B[3]);
      }
    }
    // softmax over 4 (both pixels)
    {
      float m1 = fmaxf(fmaxf(s1A[0], s1A[1]), fmaxf(s1A[2], s1A[3]));
      float e0 = __expf(s1A[0] - m1), e1 = __expf(s1A[1] - m1), e2 = __expf(s1A[2] - m1), e3 = __expf(s1A[3] - m1);
      float inv = 1.f / (e0 + e1 + e2 + e3);
      s1A[0] = e0 * inv; s1A[1] = e1 * inv; s1A[2] = e2 * inv; s1A[3] = e3 * inv;
      float m2 = fmaxf(fmaxf(s2A[0], s2A[1]), fmaxf(s2A[2], s2A[3]));
      float f0 = __expf(s2A[0] - m2), f1 = __expf(s2A[1] - m2), f2 = __expf(s2A[2] - m2), f3 = __expf(s2A[3] - m2);
      float jnv = 1.f / (f0 + f1 + f2 + f3);
      s2A[0] = f0 * jnv; s2A[1] = f1 * jnv; s2A[2] = f2 * jnv; s2A[3] = f3 * jnv;
      float m3 = fmaxf(fmaxf(s1B[0], s1B[1]), fmaxf(s1B[2], s1B[3]));
      float g0 = __expf(s1B[0] - m3), g1 = __expf(s1B[1] - m3), g2 = __expf(s1B[2] - m3), g3 = __expf(s1B[3] - m3);
      float knv = 1.f / (g0 + g1 + g2 + g3);
      s1B[0] = g0 * knv; s1B[1] = g1 * knv; s1B[2] = g2 * knv; s1B[3] = g3 * knv;
      float m4 = fmaxf(fmaxf(s2B[0], s2B[1]), fmaxf(s2B[2], s2B[3]));
      float h0 = __expf(s2B[0] - m4), h1 = __expf(s2B[1] - m4), h2e = __expf(s2B[2] - m4), h3 = __expf(s2B[3] - m4);
      float lnv = 1.f / (h0 + h1 + h2e + h3);
      s2B[0] = h0 * lnv; s2B[1] = h1 * lnv; s2B[2] = h2e * lnv; s2B[3] = h3 * lnv;
    }

    // ---- values fused with emb1 ----
    float hvA[24], hvB[24];
    {
      float q1lA = s1A[0] + s1A[2], q1hA = s1A[1] + s1A[3];
      float q2lA = s2A[0] + s2A[2], q2hA = s2A[1] + s2A[3];
      float q1lB = s1B[0] + s1B[2], q1hB = s1B[1] + s1B[3];
      float q2lB = s2B[0] + s2B[2], q2hB = s2B[1] + s2B[3];
#pragma unroll
      for (int o = 0; o < 24; o++) {
        U4 qq = ld4(W, F_Q4 + 4 * o);
        float be = W[F_BE1 + o];
        hvA[o] = fmaf(q1lA, qq.f[0], fmaf(q1hA, qq.f[1], fmaf(q2lA, qq.f[2], fmaf(q2hA, qq.f[3], be))));
        hvB[o] = fmaf(q1lB, qq.f[0], fmaf(q1hB, qq.f[1], fmaf(q2lB, qq.f[2], fmaf(q2hB, qq.f[3], be))));
      }
    }
#pragma unroll 1
    for (int cp = 0; cp < 24; cp++) {
      __half2 u0A = Xh[0][cp][tid], u1A = Xh[1][cp][tid];
      __half2 u0B = Xh[0][cp][tid + 128], u1B = Xh[1][cp][tid + 128];
#pragma unroll
      for (int ch = 0; ch < 2; ch++) {
        int c = 2 * cp + ch;
        float x0A = ch ? __high2float(u0A) : __low2float(u0A);
        float x1A = ch ? __high2float(u1A) : __low2float(u1A);
        float x0B = ch ? __high2float(u0B) : __low2float(u0B);
        float x1B = ch ? __high2float(u1B) : __low2float(u1B);
        h2 pABA = pk(fmaf(s1A[0], x0A, s1A[2] * x1A), fmaf(s1A[1], x0A, s1A[3] * x1A));
        h2 pCDA = pk(fmaf(s2A[0], x0A, s2A[2] * x1A), fmaf(s2A[1], x0A, s2A[3] * x1A));
        h2 pABB = pk(fmaf(s1B[0], x0B, s1B[2] * x1B), fmaf(s1B[1], x0B, s1B[3] * x1B));
        h2 pCDB = pk(fmaf(s2B[0], x0B, s2B[2] * x1B), fmaf(s2B[1], x0B, s2B[3] * x1B));
        const int base = H_PV + c * 48;
#pragma unroll
        for (int q = 0; q < 6; q++) {
          U4 w = ld4(W, base + 4 * q);
#pragma unroll
          for (int e = 0; e < 4; e++) {
            hvA[4 * q + e] = fdot2f(w.h[e], pABA, hvA[4 * q + e]);
            hvB[4 * q + e] = fdot2f(w.h[e], pABB, hvB[4 * q + e]);
          }
        }
#pragma unroll
        for (int q = 0; q < 6; q++) {
          U4 w = ld4(W, base + 24 + 4 * q);
#pragma unroll
          for (int e = 0; e < 4; e++) {
            hvA[4 * q + e] = fdot2f(w.h[e], pCDA, hvA[4 * q + e]);
            hvB[4 * q + e] = fdot2f(w.h[e], pCDB, hvB[4 * q + e]);
          }
        }
      }
    }
#pragma unroll
    for (int o = 0; o < 24; o++) { hA[o] = gelu_f(hvA[o]); hB[o] = gelu_f(hvB[o]); }
  }

  // ---- final: out = WE2 h + BE2 ----
  float* po = out + (size_t)b * 48 * HWS + n;
#pragma unroll 1
  for (int op = 0; op < 24; op++) {
    const float* w0 = &W[F_WE2 + op * 52];
    float a0A = w0[48], a1A = w0[49], a0B = w0[48], a1B = w0[49];
#pragma unroll
    for (int j = 0; j < 24; j++) { float ww = w0[j]; a0A = fmaf(ww, hA[j], a0A); a0B = fmaf(ww, hB[j], a0B); }
#pragma unroll
    for (int j = 0; j < 24; j++) { float ww = w0[24 + j]; a1A = fmaf(ww, hA[j], a1A); a1B = fmaf(ww, hB[j], a1B); }
    po[(size_t)(2 * op) * HWS] = a0A;
    po[(size_t)(2 * op + 1) * HWS] = a1A;
    po[(size_t)(2 * op) * HWS + 128] = a0B;
    po[(size_t)(2 * op + 1) * HWS + 128] = a1B;
  }
}

extern "C" void kernel_launch(void* const* d_in, const int* in_sizes, int n_in,
                              void* d_out, int out_size, void* d_ws, size_t ws_size,
                              hipStream_t stream) {
  PtrPack P;
  for (int i = 0; i < 48; i++) P.p[i] = (const float*)d_in[i];
  float* W = (float*)d_ws;

  fold_kernel<<<(WS_TOTAL + 255) / 256, 256, 0, stream>>>(P, W);
  fused_main<<<NPIX / BPX, T, 0, stream>>>(P.p[0], P.p[1], W, (float*)d_out);
}